// Round 13
// baseline (125.344 us; speedup 1.0000x reference)
//
#include <hip/hip_runtime.h>
#include <stdint.h>

#define BB   16
#define NGT  128
#define LL   8400
#define CC   80
#define KTOP 13
#define CAP  1024
#define FEPS 1e-9f

typedef float vfloat4 __attribute__((ext_vector_type(4)));

__device__ __forceinline__ float iou_f(float4 g, float4 p) {
    float ix0 = fmaxf(g.x, p.x);
    float iy0 = fmaxf(g.y, p.y);
    float ix1 = fminf(g.z, p.z);
    float iy1 = fminf(g.w, p.w);
    float ow = fmaxf(ix1 - ix0, 0.0f);
    float oh = fmaxf(iy1 - iy0, 0.0f);
    float ov = ow * oh;
    float a1 = fmaxf(g.z - g.x, 0.0f) * fmaxf(g.w - g.y, 0.0f);
    float a2 = fmaxf(p.z - p.x, 0.0f) * fmaxf(p.w - p.y, 0.0f);
    return ov / (a1 + a2 - ov + FEPS);
}

// 13-deep descending insertion in NAMED registers.
#define SORT2(a,b) { unsigned long long _t=(a), _u=(b); (a)=(_u>_t)?_u:_t; (b)=(_u>_t)?_t:_u; }
#define INSERT13(key) do { unsigned long long _k=(key); if (_k > k12) { k12=_k; \
    SORT2(k11,k12) SORT2(k10,k11) SORT2(k9,k10) SORT2(k8,k9) SORT2(k7,k8) \
    SORT2(k6,k7)  SORT2(k5,k6)  SORT2(k4,k5) SORT2(k3,k4) SORT2(k2,k3) \
    SORT2(k1,k2)  SORT2(k0,k1) } } while(0)
#define POP13() { k0=k1;k1=k2;k2=k3;k3=k4;k4=k5;k5=k6;k6=k7;k7=k8;k8=k9;k9=k10;k10=k11;k11=k12;k12=0ull; }

// ---- Kernel 1: PAIR-PARALLEL candidate generation -------------------------
// Thread <-> (j, i) pair: t = j*128 + i. anchors[j] and pred_bboxes[b][j]
// are wave-uniform (one broadcast line each); gt_bboxes[i]/gt_labels[i] are
// perfectly coalesced. No LDS, no syncthreads, no serial chains; 67.2K
// blocks of elementwise work. Appends key for inside && iou>0 && metric>0
// pairs; metric==0 pairs reconstructed analytically in select_kernel.
__global__ __launch_bounds__(256) void cand_kernel(
    const float*  __restrict__ pred_scores,   // B,L,C
    const float4* __restrict__ pred_bboxes,   // B,L
    const float2* __restrict__ anchors,       // L
    const int*    __restrict__ gt_labels,     // B,n
    const float4* __restrict__ gt_bboxes,     // B,n
    unsigned long long* __restrict__ records, // B*n x CAP
    int* __restrict__ cand_cnt)               // B*n (zeroed)
{
    int b = blockIdx.y;
    int p = blockIdx.x * 256 + threadIdx.x;   // pair index: j*128 + i
    int j = p >> 7;
    int i = p & (NGT - 1);

    float2 ap  = anchors[j];                        // wave-broadcast
    float4 pbx = pred_bboxes[(size_t)b * LL + j];   // wave-broadcast
    float4 gg  = gt_bboxes[b * NGT + i];            // coalesced

    float d = fminf(fminf(ap.x - gg.x, ap.y - gg.y),
                    fminf(gg.z - ap.x, gg.w - ap.y));
    if (d > FEPS) {
        float io = iou_f(gg, pbx);
        if (io > 0.0f) {
            float s  = pred_scores[((size_t)b * LL + j) * CC + gt_labels[b * NGT + i]];
            float i2 = io * io;
            float met = s * (i2 * i2 * i2);
            if (met > 0.0f) {
                int rrow = b * NGT + i;
                int slot = atomicAdd(cand_cnt + rrow, 1);
                if (slot < CAP)
                    records[(size_t)rrow * CAP + slot] =
                        ((unsigned long long)__float_as_uint(met) << 32)
                        | (unsigned)(~(unsigned)j);
            }
        }
    }
}

// ---- Kernel 2: per-row exact top-13 + fused claim --------------------------
// One wave per row. Positives from the record list (or per-row GT-major
// rescan fallback if overflow / small ws). Merge: 13 rounds wave-argmax+pop.
// Fill (P<13): the reference's remaining slots are the (13-P) smallest j
// with metric==0 == smallest j not in the positive set; provably < 26, so
// a 64-bit ballot over j=0..63 suffices. Claims: positives are provably
// in-box (no recheck); fills recheck d>FEPS.
__global__ __launch_bounds__(64) void select_kernel(
    const float*  __restrict__ pred_scores,
    const float4* __restrict__ pred_bboxes,
    const float2* __restrict__ anchors,
    const int*    __restrict__ gt_labels,
    const float4* __restrict__ gt_bboxes,
    const unsigned long long* __restrict__ records,
    const int* __restrict__ cand_cnt,
    int force_fallback,
    int* __restrict__ claim_count,
    int* __restrict__ claimant)
{
    int lane = threadIdx.x;
    int row  = blockIdx.x;               // b*NGT + i
    int b    = row >> 7;
    int i_gt = row & (NGT - 1);

    float4 g = gt_bboxes[row];
    unsigned long long k0=0,k1=0,k2=0,k3=0,k4=0,k5=0,k6=0,k7=0,k8=0,k9=0,k10=0,k11=0,k12=0;

    int cnt = cand_cnt[row];
    if (force_fallback || cnt > CAP) {
        // GT-major rescan (rare/never): positives only, same key semantics.
        int label = gt_labels[row];
        const float*  sc = pred_scores + (size_t)b * LL * CC + label;
        const float4* pb = pred_bboxes + (size_t)b * LL;
        for (int j = lane; j < LL; j += 64) {
            float2 ap = anchors[j];
            float d = fminf(fminf(ap.x - g.x, ap.y - g.y),
                            fminf(g.z - ap.x, g.w - ap.y));
            if (d > FEPS) {
                float4 p = pb[j];
                float iou = iou_f(g, p);
                if (iou > 0.0f) {
                    float s  = sc[(size_t)j * CC];
                    float i2 = iou * iou;
                    float met = s * (i2 * i2 * i2);
                    if (met > 0.0f)
                        INSERT13(((unsigned long long)__float_as_uint(met) << 32)
                                 | (unsigned)(~(unsigned)j));
                }
            }
        }
    } else {
        const unsigned long long* rr = records + (size_t)row * CAP;
        for (int t = lane; t < cnt; t += 64)
            INSERT13(rr[t]);
    }

    // ---- Merge: 13 rounds wave-argmax + owner-pop; winners -> lanes 0..12 ----
    unsigned long long winner = 0ull;
    for (int r = 0; r < KTOP; ++r) {
        unsigned long long head = k0;
        unsigned long long m = head;
#pragma unroll
        for (int off = 1; off < 64; off <<= 1) {
            unsigned long long o = __shfl_xor(m, off, 64);
            if (o > m) m = o;
        }
        if (head == m && m != 0ull) {   // unique owner (keys distinct)
            POP13();
        }
        if (lane == r) winner = m;
    }

    int jwv = -1;
    if (lane < KTOP && winner != 0ull)
        jwv = (int)(~(unsigned)(winner & 0xFFFFFFFFull));

    // positive set membership for j = 0..63 (one j per lane)
    bool marked = false;
    for (int r = 0; r < KTOP; ++r) {
        int jv = __shfl(jwv, r, 64);
        if (jv == lane) marked = true;
    }
    unsigned long long nonpos = ~__ballot(marked);
    int P = __popcll(__ballot(jwv >= 0));

    int base = b * LL;
    // positive claims (provably in-box)
    if (jwv >= 0) {
        atomicAdd(claim_count + base + jwv, 1);
        atomicMax(claimant + base + jwv, i_gt);
    }
    // fill claims: lanes P..12 take the (lane-P+1)-th smallest non-positive j
    if (lane >= P && lane < KTOP) {
        unsigned long long mask = nonpos;
        for (int t = 0; t < lane - P; ++t) mask &= mask - 1ull;
        int jf = __ffsll(mask) - 1;
        float2 ap = anchors[jf];
        float d = fminf(fminf(ap.x - g.x, ap.y - g.y),
                        fminf(g.z - ap.x, g.w - ap.y));
        if (d > FEPS) {
            atomicAdd(claim_count + base + jf, 1);
            atomicMax(claimant + base + jf, i_gt);
        }
    }
}

// ------- Kernel C: resolve contested + per-GT maxes + labels/bboxes --------
__global__ __launch_bounds__(256) void resolve_kernel(
    const float*  __restrict__ pred_scores,
    const float4* __restrict__ pred_bboxes,
    const int*    __restrict__ gt_labels,
    const float4* __restrict__ gt_bboxes,
    const int*    __restrict__ claim_count,
    const int*    __restrict__ claimant,
    int*      __restrict__ assigned_gt,
    float*    __restrict__ align_anchor,
    unsigned* __restrict__ max_metric,
    unsigned* __restrict__ max_iou,
    float*    __restrict__ out_labels,
    float4*   __restrict__ out_bboxes)
{
    int b = blockIdx.y;
    int j = blockIdx.x * 256 + threadIdx.x;

    __shared__ float4 gbox[NGT];
    __shared__ int    glab[NGT];
    if (threadIdx.x < NGT) {
        gbox[threadIdx.x] = gt_bboxes[b * NGT + threadIdx.x];
        glab[threadIdx.x] = gt_labels[b * NGT + threadIdx.x];
    }
    __syncthreads();
    if (j >= LL) return;

    int idx = b * LL + j;
    int cnt = claim_count[idx];
    int g = -1;
    float4 p = pred_bboxes[(size_t)b * LL + j];

    if (cnt == 1) {
        g = claimant[idx];
    } else if (cnt > 1) {
        // argmax_i iou over ALL gts, first-max tie-break (strict >)
        float best = -1.0f;
        int   bi   = 0;
        for (int i = 0; i < NGT; ++i) {
            float iou = iou_f(gbox[i], p);
            if (iou > best) { best = iou; bi = i; }
        }
        g = bi;
    }
    assigned_gt[idx] = g;

    int label; float4 bb;
    if (g >= 0) {
        float iou = iou_f(gbox[g], p);
        float s   = pred_scores[((size_t)b * LL + j) * CC + glab[g]];
        float i2  = iou * iou;
        float al  = s * (i2 * i2 * i2);
        align_anchor[idx] = al;
        atomicMax(max_metric + b * NGT + g, __float_as_uint(al));
        atomicMax(max_iou    + b * NGT + g, __float_as_uint(iou));
        label = glab[g];
        bb    = gbox[g];
    } else {
        label = CC;          // 80 = NUM_CLASSES
        bb    = gbox[0];     // argmax of all-zero mask -> gt 0
    }
    out_labels[idx] = (float)label;
    out_bboxes[idx] = bb;
}

// ------- Kernel E: scores — 64 anchors/block, regular coalesced stores -----
__global__ __launch_bounds__(256) void score_kernel(
    const int*    __restrict__ gt_labels,
    const int*    __restrict__ assigned_gt,
    const float*  __restrict__ align_anchor,
    const unsigned* __restrict__ max_metric,
    const unsigned* __restrict__ max_iou,
    float*  __restrict__ out_scores)
{
    __shared__ int   s_lab[64];
    __shared__ float s_f[64];

    if (threadIdx.x < 64) {
        int t = blockIdx.x * 64 + threadIdx.x;   // global anchor (exact: 2100*64)
        int b = t / LL;
        int g = assigned_gt[t];
        int label = CC;
        float f = 0.0f;
        if (g >= 0) {
            label = gt_labels[b * NGT + g];
            float mm = __uint_as_float(max_metric[b * NGT + g]);
            float mi = __uint_as_float(max_iou[b * NGT + g]);
            f = align_anchor[t] / (mm + FEPS) * mi;
        }
        s_lab[threadIdx.x] = label;
        s_f[threadIdx.x]   = f;
    }
    __syncthreads();

    // 64 anchors * 20 float4 = 1280 float4/block, 5 coalesced rounds.
    vfloat4* outs = (vfloat4*)(out_scores + (size_t)blockIdx.x * 64 * CC);
#pragma unroll
    for (int k = 0; k < 5; ++k) {
        int i = k * 256 + threadIdx.x;
        int anchor = i / (CC / 4);
        int c4     = i % (CC / 4);
        int lab    = s_lab[anchor];
        vfloat4 v = {0.f, 0.f, 0.f, 0.f};
        int rel = lab - c4 * 4;
        if (rel >= 0 && rel < 4) v[rel] = s_f[anchor];
        outs[i] = v;                       // regular store (L2 write-back)
    }
}

extern "C" void kernel_launch(void* const* d_in, const int* in_sizes, int n_in,
                              void* d_out, int out_size, void* d_ws, size_t ws_size,
                              hipStream_t stream)
{
    const float*  pred_scores = (const float*)d_in[0];
    const float4* pred_bboxes = (const float4*)d_in[1];
    const float2* anchors     = (const float2*)d_in[2];
    const int*    gt_labels   = (const int*)d_in[3];
    const float4* gt_bboxes   = (const float4*)d_in[4];
    // d_in[5] = pad_gt_mask (all ones by construction)

    char* w = (char*)d_ws;
    // zeroed region (one memset):
    int*      claim_count  = (int*)(w);                 // B*L  = 537600 B
    int*      claimant     = (int*)(w + 537600);        // B*L  = 537600 B
    unsigned* max_metric   = (unsigned*)(w + 1075200);  // B*n  =   8192 B
    unsigned* max_iou      = (unsigned*)(w + 1083392);  // B*n  =   8192 B
    int*      cand_cnt     = (int*)(w + 1091584);       // B*n  =   8192 B
    // non-zeroed (fully overwritten / count-guarded):
    int*      assigned_gt  = (int*)(w + 1099776);       // B*L  = 537600 B
    float*    align_anchor = (float*)(w + 1637376);     // B*L  = 537600 B
    unsigned long long* records = (unsigned long long*)(w + 2174976); // 16.8 MB

    const size_t WS_NEEDED = 2174976ull + (size_t)BB * NGT * CAP * 8ull; // ~18.95 MB
    int force_fallback = (ws_size < WS_NEEDED) ? 1 : 0;

    float*  out        = (float*)d_out;
    float*  out_labels = out;                                   // B*L
    float4* out_bboxes = (float4*)(out + (size_t)BB * LL);      // B*L*4
    float*  out_scores = out + (size_t)BB * LL * 5;             // B*L*80

    (void)hipMemsetAsync(w, 0, 1099776, stream);

    if (!force_fallback) {
        dim3 gridG(LL * NGT / 256, BB);   // 4200 x 16 blocks, pair-parallel
        cand_kernel<<<gridG, 256, 0, stream>>>(
            pred_scores, pred_bboxes, anchors, gt_labels, gt_bboxes,
            records, cand_cnt);
    }

    select_kernel<<<BB * NGT, 64, 0, stream>>>(
        pred_scores, pred_bboxes, anchors, gt_labels, gt_bboxes,
        records, cand_cnt, force_fallback, claim_count, claimant);

    dim3 gridC((LL + 255) / 256, BB);
    resolve_kernel<<<gridC, 256, 0, stream>>>(
        pred_scores, pred_bboxes, gt_labels, gt_bboxes,
        claim_count, claimant, assigned_gt, align_anchor, max_metric, max_iou,
        out_labels, out_bboxes);

    score_kernel<<<(BB * LL) / 64, 256, 0, stream>>>(
        gt_labels, assigned_gt, align_anchor, max_metric, max_iou, out_scores);
}

// Round 14
// 93.337 us; speedup vs baseline: 1.3429x; 1.3429x over previous
//
#include <hip/hip_runtime.h>
#include <stdint.h>

#define BB    16
#define NGT   128
#define LL    8400
#define CC    80
#define KTOP  13
#define FEPS  1e-9f
#define NCELL 10          // 10x10 grid of 64px cells over [0,640]^2
#define SLOTS 128         // max anchors per cell (mean 84, +4.8 sigma)

typedef float vfloat4 __attribute__((ext_vector_type(4)));

__device__ __forceinline__ float iou_f(float4 g, float4 p) {
    float ix0 = fmaxf(g.x, p.x);
    float iy0 = fmaxf(g.y, p.y);
    float ix1 = fminf(g.z, p.z);
    float iy1 = fminf(g.w, p.w);
    float ow = fmaxf(ix1 - ix0, 0.0f);
    float oh = fmaxf(iy1 - iy0, 0.0f);
    float ov = ow * oh;
    float a1 = fmaxf(g.z - g.x, 0.0f) * fmaxf(g.w - g.y, 0.0f);
    float a2 = fmaxf(p.z - p.x, 0.0f) * fmaxf(p.w - p.y, 0.0f);
    return ov / (a1 + a2 - ov + FEPS);
}

// 13-deep descending insertion in NAMED registers.
#define SORT2(a,b) { unsigned long long _t=(a), _u=(b); (a)=(_u>_t)?_u:_t; (b)=(_u>_t)?_t:_u; }
#define INSERT13(key) do { unsigned long long _k=(key); if (_k > k12) { k12=_k; \
    SORT2(k11,k12) SORT2(k10,k11) SORT2(k9,k10) SORT2(k8,k9) SORT2(k7,k8) \
    SORT2(k6,k7)  SORT2(k5,k6)  SORT2(k4,k5) SORT2(k3,k4) SORT2(k2,k3) \
    SORT2(k1,k2)  SORT2(k0,k1) } } while(0)
#define POP13() { k0=k1;k1=k2;k2=k3;k3=k4;k4=k5;k5=k6;k6=k7;k7=k8;k8=k9;k9=k10;k10=k11;k11=k12;k12=0ull; }

// ---- Kernel 1: prep = anchor binning (block 0, LDS) + array zeroing -------
// Replaces the hipMemset dispatch AND the candidate-generation kernel.
__global__ __launch_bounds__(256) void prep_kernel(
    const float2* __restrict__ anchors,   // L
    int* __restrict__ bin_cnt,            // 100
    int* __restrict__ bins,               // 100*SLOTS
    int* __restrict__ overflow,           // 1
    int* __restrict__ zero_base,          // 272896 words to zero
    int  zero_words)
{
    if (blockIdx.x == 0) {
        __shared__ int lcnt[NCELL * NCELL];
        __shared__ int lbins[NCELL * NCELL * SLOTS];   // 51.2 KB
        for (int i = threadIdx.x; i < NCELL * NCELL; i += 256) lcnt[i] = 0;
        if (threadIdx.x == 0) *overflow = 0;
        __syncthreads();
        for (int j = threadIdx.x; j < LL; j += 256) {
            float2 ap = anchors[j];
            int cx = (int)(ap.x * (1.0f / 64.0f));
            int cy = (int)(ap.y * (1.0f / 64.0f));
            cx = min(max(cx, 0), NCELL - 1);
            cy = min(max(cy, 0), NCELL - 1);
            int c = cy * NCELL + cx;
            int slot = atomicAdd(&lcnt[c], 1);
            if (slot < SLOTS) lbins[c * SLOTS + slot] = j;
            else              *overflow = 1;
        }
        __syncthreads();
        for (int i = threadIdx.x; i < NCELL * NCELL; i += 256)
            bin_cnt[i] = min(lcnt[i], SLOTS);
        for (int i = threadIdx.x; i < NCELL * NCELL * SLOTS; i += 256)
            bins[i] = lbins[i];
    } else {
        int t = (blockIdx.x - 1) * 256 + threadIdx.x;
        if (t < zero_words) zero_base[t] = 0;
    }
}

// ---- Kernel 2: per-row exact top-13 + fused claim (bin-accelerated) -------
// One block (4 waves) per row. Candidates come only from grid cells
// overlapping the GT box (<=25 cells, ~700 anchors vs 8400). Positives
// (inside && iou>0 && metric>0) go through INSERT13; per-wave merge then
// wave-0 merge of 4x13. Fill (P<13): reference's remaining slots are the
// (13-P) smallest j with metric==0 (provably < 26) -> 64-lane ballot.
// Claims: positives provably in-box (no recheck); fills recheck d>FEPS.
// Key = (metric_bits<<32) | ~j -> (value desc, index asc) == jax.lax.top_k.
__global__ __launch_bounds__(256) void select_kernel(
    const float*  __restrict__ pred_scores,
    const float4* __restrict__ pred_bboxes,
    const float2* __restrict__ anchors,
    const int*    __restrict__ gt_labels,
    const float4* __restrict__ gt_bboxes,
    const int*    __restrict__ bin_cnt,
    const int*    __restrict__ bins,
    const int*    __restrict__ overflow,
    int* __restrict__ claim_count,
    int* __restrict__ claimant)
{
    int tid  = threadIdx.x;
    int wave = tid >> 6;
    int lane = tid & 63;
    int row  = blockIdx.x;               // b*NGT + i
    int b    = row >> 7;
    int i_gt = row & (NGT - 1);

    float4 g  = gt_bboxes[row];
    int label = gt_labels[row];
    const float*  sc = pred_scores + (size_t)b * LL * CC + label;
    const float4* pb = pred_bboxes + (size_t)b * LL;

    unsigned long long k0=0,k1=0,k2=0,k3=0,k4=0,k5=0,k6=0,k7=0,k8=0,k9=0,k10=0,k11=0,k12=0;

    if (*overflow) {
        // fallback: strided full scan (never expected; correctness-safe)
        for (int j = tid; j < LL; j += 256) {
            float2 ap = anchors[j];
            float d = fminf(fminf(ap.x - g.x, ap.y - g.y),
                            fminf(g.z - ap.x, g.w - ap.y));
            if (d > FEPS) {
                float4 p = pb[j];
                float io = iou_f(g, p);
                if (io > 0.0f) {
                    float s  = sc[(size_t)j * CC];
                    float i2 = io * io;
                    float met = s * (i2 * i2 * i2);
                    if (met > 0.0f)
                        INSERT13(((unsigned long long)__float_as_uint(met) << 32)
                                 | (unsigned)(~(unsigned)j));
                }
            }
        }
    } else {
        int cx0 = min(max((int)(g.x * (1.0f / 64.0f)), 0), NCELL - 1);
        int cy0 = min(max((int)(g.y * (1.0f / 64.0f)), 0), NCELL - 1);
        int cx1 = min(max((int)(g.z * (1.0f / 64.0f)), 0), NCELL - 1);
        int cy1 = min(max((int)(g.w * (1.0f / 64.0f)), 0), NCELL - 1);
        int ncx = cx1 - cx0 + 1;
        int ncells = ncx * (cy1 - cy0 + 1);
        for (int c = wave; c < ncells; c += 4) {
            int cell = (cy0 + c / ncx) * NCELL + (cx0 + c % ncx);
            int cnt  = bin_cnt[cell];
            const int* cb = bins + cell * SLOTS;
            for (int s = lane; s < cnt; s += 64) {
                int j = cb[s];
                float2 ap = anchors[j];
                float d = fminf(fminf(ap.x - g.x, ap.y - g.y),
                                fminf(g.z - ap.x, g.w - ap.y));
                if (d > FEPS) {
                    float4 p = pb[j];
                    float io = iou_f(g, p);
                    if (io > 0.0f) {
                        float sv = sc[(size_t)j * CC];
                        float i2 = io * io;
                        float met = sv * (i2 * i2 * i2);
                        if (met > 0.0f)
                            INSERT13(((unsigned long long)__float_as_uint(met) << 32)
                                     | (unsigned)(~(unsigned)j));
                    }
                }
            }
        }
    }

    // ---- Stage 1: per-wave top-13 (13 rounds wave-argmax + owner-pop) ----
    __shared__ unsigned long long wkeys[4 * KTOP];
    for (int r = 0; r < KTOP; ++r) {
        unsigned long long head = k0;
        unsigned long long m = head;
#pragma unroll
        for (int off = 1; off < 64; off <<= 1) {
            unsigned long long o = __shfl_xor(m, off, 64);
            if (o > m) m = o;
        }
        if (head == m && m != 0ull) POP13();
        if (lane == 0) wkeys[wave * KTOP + r] = m;
    }
    __syncthreads();

    // ---- Stage 2 (wave 0): merge 4x13, then fills + parallel claims ----
    if (wave == 0) {
        unsigned long long kk = (lane < 4 * KTOP) ? wkeys[lane] : 0ull;
        unsigned long long winner = 0ull;
        for (int r = 0; r < KTOP; ++r) {
            unsigned long long m = kk;
#pragma unroll
            for (int off = 1; off < 64; off <<= 1) {
                unsigned long long o = __shfl_xor(m, off, 64);
                if (o > m) m = o;
            }
            if (kk == m && m != 0ull) kk = 0ull;   // pop
            if (lane == r) winner = m;
        }

        int jwv = -1;
        if (lane < KTOP && winner != 0ull)
            jwv = (int)(~(unsigned)(winner & 0xFFFFFFFFull));

        // positive-set membership for j = 0..63 (one j per lane)
        bool marked = false;
        for (int r = 0; r < KTOP; ++r) {
            int jv = __shfl(jwv, r, 64);
            if (jv == lane) marked = true;
        }
        unsigned long long nonpos = ~__ballot(marked);
        int P = __popcll(__ballot(jwv >= 0));

        int base = b * LL;
        if (jwv >= 0) {                        // positive claims
            atomicAdd(claim_count + base + jwv, 1);
            atomicMax(claimant + base + jwv, i_gt);
        }
        if (lane >= P && lane < KTOP) {        // fill claims
            unsigned long long mask = nonpos;
            for (int t = 0; t < lane - P; ++t) mask &= mask - 1ull;
            int jf = __ffsll(mask) - 1;
            float2 ap = anchors[jf];
            float d = fminf(fminf(ap.x - g.x, ap.y - g.y),
                            fminf(g.z - ap.x, g.w - ap.y));
            if (d > FEPS) {
                atomicAdd(claim_count + base + jf, 1);
                atomicMax(claimant + base + jf, i_gt);
            }
        }
    }
}

// ------- Kernel C: resolve contested + per-GT maxes + labels/bboxes --------
__global__ __launch_bounds__(256) void resolve_kernel(
    const float*  __restrict__ pred_scores,
    const float4* __restrict__ pred_bboxes,
    const int*    __restrict__ gt_labels,
    const float4* __restrict__ gt_bboxes,
    const int*    __restrict__ claim_count,
    const int*    __restrict__ claimant,
    int*      __restrict__ assigned_gt,
    float*    __restrict__ align_anchor,
    unsigned* __restrict__ max_metric,
    unsigned* __restrict__ max_iou,
    float*    __restrict__ out_labels,
    float4*   __restrict__ out_bboxes)
{
    int b = blockIdx.y;
    int j = blockIdx.x * 256 + threadIdx.x;

    __shared__ float4 gbox[NGT];
    __shared__ int    glab[NGT];
    if (threadIdx.x < NGT) {
        gbox[threadIdx.x] = gt_bboxes[b * NGT + threadIdx.x];
        glab[threadIdx.x] = gt_labels[b * NGT + threadIdx.x];
    }
    __syncthreads();
    if (j >= LL) return;

    int idx = b * LL + j;
    int cnt = claim_count[idx];
    int g = -1;
    float4 p = pred_bboxes[(size_t)b * LL + j];

    if (cnt == 1) {
        g = claimant[idx];
    } else if (cnt > 1) {
        // argmax_i iou over ALL gts, first-max tie-break (strict >)
        float best = -1.0f;
        int   bi   = 0;
        for (int i = 0; i < NGT; ++i) {
            float iou = iou_f(gbox[i], p);
            if (iou > best) { best = iou; bi = i; }
        }
        g = bi;
    }
    assigned_gt[idx] = g;

    int label; float4 bb;
    if (g >= 0) {
        float iou = iou_f(gbox[g], p);
        float s   = pred_scores[((size_t)b * LL + j) * CC + glab[g]];
        float i2  = iou * iou;
        float al  = s * (i2 * i2 * i2);
        align_anchor[idx] = al;
        atomicMax(max_metric + b * NGT + g, __float_as_uint(al));
        atomicMax(max_iou    + b * NGT + g, __float_as_uint(iou));
        label = glab[g];
        bb    = gbox[g];
    } else {
        label = CC;          // 80 = NUM_CLASSES
        bb    = gbox[0];     // argmax of all-zero mask -> gt 0
    }
    out_labels[idx] = (float)label;
    out_bboxes[idx] = bb;
}

// ------- Kernel E: scores — 64 anchors/block, regular coalesced stores -----
__global__ __launch_bounds__(256) void score_kernel(
    const int*    __restrict__ gt_labels,
    const int*    __restrict__ assigned_gt,
    const float*  __restrict__ align_anchor,
    const unsigned* __restrict__ max_metric,
    const unsigned* __restrict__ max_iou,
    float*  __restrict__ out_scores)
{
    __shared__ int   s_lab[64];
    __shared__ float s_f[64];

    if (threadIdx.x < 64) {
        int t = blockIdx.x * 64 + threadIdx.x;   // global anchor (exact: 2100*64)
        int b = t / LL;
        int g = assigned_gt[t];
        int label = CC;
        float f = 0.0f;
        if (g >= 0) {
            label = gt_labels[b * NGT + g];
            float mm = __uint_as_float(max_metric[b * NGT + g]);
            float mi = __uint_as_float(max_iou[b * NGT + g]);
            f = align_anchor[t] / (mm + FEPS) * mi;
        }
        s_lab[threadIdx.x] = label;
        s_f[threadIdx.x]   = f;
    }
    __syncthreads();

    // 64 anchors * 20 float4 = 1280 float4/block, 5 coalesced rounds.
    vfloat4* outs = (vfloat4*)(out_scores + (size_t)blockIdx.x * 64 * CC);
#pragma unroll
    for (int k = 0; k < 5; ++k) {
        int i = k * 256 + threadIdx.x;
        int anchor = i / (CC / 4);
        int c4     = i % (CC / 4);
        int lab    = s_lab[anchor];
        vfloat4 v = {0.f, 0.f, 0.f, 0.f};
        int rel = lab - c4 * 4;
        if (rel >= 0 && rel < 4) v[rel] = s_f[anchor];
        outs[i] = v;
    }
}

extern "C" void kernel_launch(void* const* d_in, const int* in_sizes, int n_in,
                              void* d_out, int out_size, void* d_ws, size_t ws_size,
                              hipStream_t stream)
{
    const float*  pred_scores = (const float*)d_in[0];
    const float4* pred_bboxes = (const float4*)d_in[1];
    const float2* anchors     = (const float2*)d_in[2];
    const int*    gt_labels   = (const int*)d_in[3];
    const float4* gt_bboxes   = (const float4*)d_in[4];
    // d_in[5] = pad_gt_mask (all ones by construction)

    char* w = (char*)d_ws;
    // zeroed by prep_kernel (blocks 1..): claim_count, claimant, maxes
    int*      claim_count  = (int*)(w);                 // B*L  = 537600 B
    int*      claimant     = (int*)(w + 537600);        // B*L  = 537600 B
    unsigned* max_metric   = (unsigned*)(w + 1075200);  // B*n  =   8192 B
    unsigned* max_iou      = (unsigned*)(w + 1083392);  // B*n  =   8192 B
    // written before read:
    int*      assigned_gt  = (int*)(w + 1091584);       // B*L  = 537600 B
    float*    align_anchor = (float*)(w + 1629184);     // B*L  = 537600 B
    int*      bin_cnt      = (int*)(w + 2166784);       // 100 ints (pad 512)
    int*      overflow     = (int*)(w + 2167296);       // 1 int  (pad 256)
    int*      bins         = (int*)(w + 2167552);       // 100*128*4 = 51200 B

    const int ZERO_WORDS = 1091584 / 4;                 // 272896

    float*  out        = (float*)d_out;
    float*  out_labels = out;                                   // B*L
    float4* out_bboxes = (float4*)(out + (size_t)BB * LL);      // B*L*4
    float*  out_scores = out + (size_t)BB * LL * 5;             // B*L*80

    int zero_blocks = (ZERO_WORDS + 255) / 256;         // 1066
    prep_kernel<<<1 + zero_blocks, 256, 0, stream>>>(
        anchors, bin_cnt, bins, overflow, (int*)w, ZERO_WORDS);

    select_kernel<<<BB * NGT, 256, 0, stream>>>(
        pred_scores, pred_bboxes, anchors, gt_labels, gt_bboxes,
        bin_cnt, bins, overflow, claim_count, claimant);

    dim3 gridC((LL + 255) / 256, BB);
    resolve_kernel<<<gridC, 256, 0, stream>>>(
        pred_scores, pred_bboxes, gt_labels, gt_bboxes,
        claim_count, claimant, assigned_gt, align_anchor, max_metric, max_iou,
        out_labels, out_bboxes);

    score_kernel<<<(BB * LL) / 64, 256, 0, stream>>>(
        gt_labels, assigned_gt, align_anchor, max_metric, max_iou, out_scores);
}